// Round 3
// baseline (182.111 us; speedup 1.0000x reference)
//
#include <hip/hip_runtime.h>
#include <math.h>

// ---------------- constants ----------------
#define NPIX 32768            // 2 * 128 * 128
#define OUT_DZ 0
#define OUT_BLUR 18432
#define OUT_LD 51200
#define OUT_REG 51201
#define OUT_TV 51202
#define NSLAB 30

__constant__ int d_cin[18] = {512,512,512,512,512,512,512,512,256,256,128,128,64,64,32,32,16,16};
__constant__ int d_H[18]   = {4,  4,  8,  16, 32, 32, 64, 128,256,256,256,256,256,256,256,256,256,256};

// slab = (layer t, channel chunk c0, chunk size nc) — balanced to ~256KB traffic each
__constant__ int d_slab_t[NSLAB]  = {0,1,2,3,4,5, 6,6, 7,7,7,7, 8,8,8,8, 9,9,9,9, 10,10, 11,11, 12,13,14,15,16,17};
__constant__ int d_slab_c0[NSLAB] = {0,0,0,0,0,0, 0,256, 0,128,256,384, 0,64,128,192, 0,64,128,192, 0,64, 0,64, 0,0,0,0,0,0};
__constant__ int d_slab_nc[NSLAB] = {512,512,512,512,512,512, 256,256, 128,128,128,128, 64,64,64,64, 64,64,64,64, 64,64, 64,64, 64,64,32,32,16,16};

struct FPtrs { const float* f[18]; };

// ws layout (float offsets)
#define WS_HA     0        // 7168
#define WS_HB     7168     // 7168
#define WS_ST     14336    // 512*16 = 8192  (-2*state transposed, [c][16])
#define WS_CN     22528    // 48
#define WS_BIASP  22576    // 18 (pad to 22656)
#define WS_V      22656    // 18*512 = 9216
#define WS_CHOICE 31872    // 32768 ints
#define WS_PART   64640    // NSLAB*32768 = 983040
#define WS_EACH   1047680  // 32768
#define WS_SUMS   1080448  // 128*20
#define WS_CNTS   1083008  // 128*20 ints
#define WS_ATTV   1085568  // 20
#define WS_TVP    1085600  // 128

// ---------------- small precompute: folded attention vectors + state transpose ----------------
__global__ __launch_bounds__(512) void k_vfold(
    const float* __restrict__ afw, const float* __restrict__ afb,
    const float* __restrict__ aw,  const float* __restrict__ ab,
    const float* __restrict__ alw, const float* __restrict__ istate,
    float* __restrict__ v, float* __restrict__ biasp,
    float* __restrict__ st, float* __restrict__ cn)
{
    int t = blockIdx.x;
    if (t < 18) {
        int cin = d_cin[t];
        const float* w  = (t==0) ? afw : aw + (size_t)(t-1)*32*512;
        const float* bb = (t==0) ? afb : ab + (t-1)*32;
        float scale = (1.0f/sqrtf((float)cin)) * (1.0f/24.0f);   // 1/sqrt(cin) * 1/sqrt(576)
        int c = threadIdx.x;
        if (c < cin) {
            float s = 0.0f;
            #pragma unroll 8
            for (int o = 0; o < 32; o++) s += alw[t*32+o] * w[o*512 + c];
            v[t*512 + c] = s * scale;
        }
        if (threadIdx.x == 0) {
            float s = 0.0f;
            for (int o = 0; o < 32; o++) s += alw[t*32+o] * bb[o];
            biasp[t] = s * (1.0f/24.0f);
        }
    } else {
        int c = threadIdx.x;
        if (c < 512) {
            #pragma unroll
            for (int j = 0; j < 10; j++) st[c*16 + j] = -2.0f * istate[j*576 + c];
        }
        if (c < 10) {
            int j = c;
            float n = 0.0f, s1 = 0.0f, s2 = 0.0f;
            for (int k = 0; k < 576; k++) { float sv = istate[j*576+k]; n += sv*sv; }
            for (int k = 512; k < 544; k++) s1 += istate[j*576+k];
            for (int k = 544; k < 576; k++) s2 += istate[j*576+k];
            cn[j] = n; cn[16+j] = -2.0f*s1; cn[32+j] = -2.0f*s2;
        }
    }
}

// ---------------- cluster assignment (split-K in-block) ----------------
__global__ __launch_bounds__(256) void k_assign(
    const float* __restrict__ blend, const float* __restrict__ st,
    const float* __restrict__ cn, int* __restrict__ choice)
{
    __shared__ float gsh[256*10];
    int tid = threadIdx.x;
    int csub = __builtin_amdgcn_readfirstlane(tid >> 6);
    int pl = tid & 63;
    int p = blockIdx.x*64 + pl;
    int b = p >> 14, rem = p & 16383;
    float g[10] = {0,0,0,0,0,0,0,0,0,0};
    const float* src = blend + ((size_t)b*512 + csub*128)*16384 + rem;
    const float* stc = st + csub*128*16;
    #pragma unroll 8
    for (int c = 0; c < 128; c++) {
        float val = src[(size_t)c << 14];
        #pragma unroll
        for (int j = 0; j < 10; j++) g[j] = fmaf(val, stc[c*16 + j], g[j]);
    }
    #pragma unroll
    for (int j = 0; j < 10; j++) gsh[tid*10 + j] = g[j];
    __syncthreads();
    if (tid < 64) {
        int pp = blockIdx.x*64 + tid;
        int bb = pp >> 14, rr = pp & 16383, y = rr >> 7, x = rr & 127;
        float cx = (float)x * (float)(2.0/127.0) - 1.0f;
        float cy = (float)y * (float)(2.0/127.0) - 1.0f;
        float gt[10];
        #pragma unroll
        for (int j = 0; j < 10; j++) {
            gt[j] = cn[j] + cn[16+j]*cx + cn[32+j]*cy
                  + gsh[tid*10 + j] + gsh[(64+tid)*10 + j]
                  + gsh[(128+tid)*10 + j] + gsh[(192+tid)*10 + j];
        }
        int best = 0; float bg = gt[0];
        #pragma unroll
        for (int j = 1; j < 10; j++) if (gt[j] < bg) { bg = gt[j]; best = j; }
        choice[pp] = bb*10 + best;
    }
}

// ---------------- mapper: RMS norm ----------------
__global__ __launch_bounds__(256) void k_norm(const float* __restrict__ x, float* __restrict__ h)
{
    int r = blockIdx.x;           // 0..13  (b*7+c)
    int b = r / 7, c = r % 7;
    const float* xr = x + ((size_t)b*18 + c)*512;
    int tid = threadIdx.x;
    float v0 = xr[tid], v1 = xr[tid+256];
    __shared__ float red[256];
    __shared__ float scale;
    red[tid] = v0*v0 + v1*v1; __syncthreads();
    for (int s = 128; s; s >>= 1) { if (tid < s) red[tid] += red[tid+s]; __syncthreads(); }
    if (tid == 0) scale = 1.0f / sqrtf(red[0]*(1.0f/512.0f) + 1e-8f);
    __syncthreads();
    h[r*512 + tid] = v0*scale; h[r*512 + 256 + tid] = v1*scale;
}

// ---------------- mapper: one MLP layer (wave per (c,o), both batches) ----------------
__global__ __launch_bounds__(256) void k_mlp(
    const float* __restrict__ mw, const float* __restrict__ mb,
    const float* __restrict__ hin, float* __restrict__ hout,
    int layer, float* __restrict__ dz)
{
    int wave = blockIdx.x*4 + (threadIdx.x >> 6);
    int lane = threadIdx.x & 63;
    int c = wave >> 9, o = wave & 511;
    const float* wrow = mw + (((size_t)(c*3 + layer)*512 + o) << 9) + lane*8;
    float4 w0 = *(const float4*)wrow;
    float4 w1 = *(const float4*)(wrow + 4);
    const float* h0 = hin + (size_t)c*512 + lane*8;
    const float* h1 = hin + (size_t)(7 + c)*512 + lane*8;
    float4 a0 = *(const float4*)h0, a1 = *(const float4*)(h0+4);
    float4 b0 = *(const float4*)h1, b1 = *(const float4*)(h1+4);
    float d0 = a0.x*w0.x + a0.y*w0.y + a0.z*w0.z + a0.w*w0.w
             + a1.x*w1.x + a1.y*w1.y + a1.z*w1.z + a1.w*w1.w;
    float d1 = b0.x*w0.x + b0.y*w0.y + b0.z*w0.z + b0.w*w0.w
             + b1.x*w1.x + b1.y*w1.y + b1.z*w1.z + b1.w*w1.w;
    #pragma unroll
    for (int m = 32; m; m >>= 1) { d0 += __shfl_xor(d0, m); d1 += __shfl_xor(d1, m); }
    if (lane == 0) {
        const float wsc = (float)(0.1/22.62741699796952);   // 0.1/sqrt(512)
        const float rt2 = 1.41421356237309515f;
        float bias = mb[(c*3 + layer)*512 + o] * 0.1f;
        float z0 = d0*wsc + bias; z0 = (z0 > 0.0f ? z0 : 0.2f*z0) * rt2;
        float z1 = d1*wsc + bias; z1 = (z1 > 0.0f ? z1 : 0.2f*z1) * rt2;
        hout[(size_t)c*512 + o] = z0;
        hout[(size_t)(7 + c)*512 + o] = z1;
        if (dz) {
            dz[((size_t)0*18 + c)*512 + o] = z0;
            dz[((size_t)1*18 + c)*512 + o] = z1;
        }
    }
}

// ---------------- loss_delta ----------------
__global__ __launch_bounds__(256) void k_lossdelta(const float* __restrict__ h, float* __restrict__ outp)
{
    __shared__ float red[256];
    int tid = threadIdx.x;
    float total = 0.0f;
    for (int r = 0; r < 14; r++) {
        float v0 = h[r*512 + tid], v1 = h[r*512 + 256 + tid];
        red[tid] = v0*v0 + v1*v1; __syncthreads();
        for (int s = 128; s; s >>= 1) { if (tid < s) red[tid] += red[tid+s]; __syncthreads(); }
        if (tid == 0) total += sqrtf(red[0]);
        __syncthreads();
    }
    if (tid == 0) outp[0] = total * (1.0f/14.0f);
}

// ---------------- zero tail of delta_zs (layers 7..17) ----------------
__global__ __launch_bounds__(256) void k_zero(float* __restrict__ out)
{
    int z = blockIdx.x*256 + threadIdx.x;   // 0..11263
    if (z < 11264) {
        int b = z / (11*512), rem = z % (11*512);
        out[(size_t)b*18*512 + 7*512 + rem] = 0.0f;
    }
}

// ---------------- balanced folded attention dots ----------------
// grid = NSLAB*64 blocks; block handles 512 pixels (4 output rows) x one channel chunk.
// thread: 2 adjacent output pixels. Wave = one output row (64 lanes * 2 px = 128).
__global__ __launch_bounds__(256) void k_each(FPtrs fp, const float* __restrict__ v, float* __restrict__ partial)
{
    int s  = blockIdx.x >> 6;
    int px = blockIdx.x & 63;
    int t  = d_slab_t[s];
    int c0 = d_slab_c0[s];
    int nc = d_slab_nc[s];
    int H  = d_H[t];
    int cin = d_cin[t];
    const float* vt = v + t*512 + c0;
    int tid  = threadIdx.x;
    int row  = tid >> 6;          // 0..3
    int lane = tid & 63;
    int pbase = px*512;
    int b = pbase >> 14;
    int y = ((pbase & 16383) >> 7) + row;
    const float* base = fp.f[t] + (size_t)(b*cin + c0) * (size_t)(H*H);
    float a0 = 0.0f, a1 = 0.0f;

    if (H == 256) {
        // sx pairs (4*lane, 4*lane+2), sy = 2y -> one float4 per channel
        const float* src = base + (size_t)(2*y)*256 + 4*lane;
        #pragma unroll 4
        for (int c = 0; c < nc; c++) {
            float4 q = *(const float4*)(src + (size_t)c*65536);
            float vv = vt[c];
            a0 = fmaf(q.x, vv, a0); a1 = fmaf(q.z, vv, a1);
        }
    } else if (H == 128) {
        const float* src = base + (size_t)y*128 + 2*lane;
        #pragma unroll 4
        for (int c = 0; c < nc; c++) {
            float2 q = *(const float2*)(src + (size_t)c*16384);
            float vv = vt[c];
            a0 = fmaf(q.x, vv, a0); a1 = fmaf(q.y, vv, a1);
        }
    } else if (H == 64) {
        // both pixels sample the same source element
        const float* src = base + (size_t)(y >> 1)*64 + lane;
        #pragma unroll 4
        for (int c = 0; c < nc; c++) {
            float q = src[(size_t)c*4096];
            float vv = vt[c];
            a0 = fmaf(q, vv, a0); a1 = fmaf(q, vv, a1);
        }
    } else {
        int x0 = 2*lane, x1 = 2*lane + 1;
        int sy = (y*H) >> 7, sx0 = (x0*H) >> 7, sx1 = (x1*H) >> 7;
        const float* src = base + (size_t)sy*H;
        size_t HH = (size_t)H*H;
        #pragma unroll 4
        for (int c = 0; c < nc; c++) {
            float vv = vt[c];
            a0 = fmaf(src[(size_t)c*HH + sx0], vv, a0);
            a1 = fmaf(src[(size_t)c*HH + sx1], vv, a1);
        }
    }
    int p = pbase + row*128 + 2*lane;
    float2 o; o.x = a0; o.y = a1;
    *(float2*)(partial + (size_t)s*NPIX + p) = o;
}

// ---------------- logits -> sigmoid -> segment partials ----------------
__global__ __launch_bounds__(256) void k_logits(
    const float* __restrict__ partial, const float* __restrict__ biasp,
    const float* __restrict__ alb, const int* __restrict__ choice,
    float* __restrict__ each, float* __restrict__ bsums, int* __restrict__ bcnts)
{
    __shared__ float ssum[20]; __shared__ int scnt[20]; __shared__ float sbias;
    int tid = threadIdx.x;
    if (tid < 20) { ssum[tid] = 0.0f; scnt[tid] = 0; }
    if (tid == 0) {
        float s = alb[0];
        for (int t = 0; t < 18; t++) s += biasp[t];
        sbias = s;
    }
    __syncthreads();
    int p = blockIdx.x*256 + tid;
    float lg = sbias;
    #pragma unroll
    for (int s = 0; s < NSLAB; s++) lg += partial[(size_t)s*NPIX + p];
    float e = 1.0f / (1.0f + expf(-lg));
    each[p] = e;
    int ch = choice[p];
    atomicAdd(&ssum[ch], e);
    atomicAdd(&scnt[ch], 1);
    __syncthreads();
    if (tid < 20) { bsums[blockIdx.x*20 + tid] = ssum[tid]; bcnts[blockIdx.x*20 + tid] = scnt[tid]; }
}

// ---------------- segment stats -> attval, loss_reg ----------------
__global__ __launch_bounds__(64) void k_stats(
    const float* __restrict__ bsums, const int* __restrict__ bcnts,
    float* __restrict__ attv, float* __restrict__ out)
{
    __shared__ float red[32];
    int j = threadIdx.x;
    float regj = 0.0f;
    if (j < 20) {
        float s = 0.0f; int c = 0;
        for (int blk = 0; blk < 128; blk++) { s += bsums[blk*20 + j]; c += bcnts[blk*20 + j]; }
        float mean = s / fmaxf((float)c, 1.0f);
        attv[j] = (c > 0) ? mean : 1.0f;
        regj = (c > 0) ? fmaxf(mean - 0.8f, 0.0f) : 0.0f;
    }
    if (j < 32) red[j] = (j < 20) ? regj : 0.0f;
    __syncthreads();
    for (int s = 16; s; s >>= 1) { if (j < s) red[j] += red[j+s]; __syncthreads(); }
    if (j == 0) out[OUT_REG] = red[0] * 0.5f;   // / batch
}

// ---------------- final map, blur, loss_tv partials ----------------
__global__ __launch_bounds__(256) void k_final(
    const float* __restrict__ each, const int* __restrict__ choice,
    const float* __restrict__ attv, float* __restrict__ tvp, float* __restrict__ out)
{
    __shared__ float av[20];
    __shared__ float red[256];
    int tid = threadIdx.x;
    if (tid < 20) av[tid] = attv[tid];
    __syncthreads();
    int p = blockIdx.x*256 + tid;
    int b = p >> 14, rem = p & 16383, y = rem >> 7, x = rem & 127;
    float k1[5]; float ks = 0.0f;
    #pragma unroll
    for (int i = 0; i < 5; i++) { float d = (float)(i-2) / 1.1f; k1[i] = expf(-0.5f*d*d); ks += k1[i]; }
    #pragma unroll
    for (int i = 0; i < 5; i++) k1[i] /= ks;
    const int* cb = choice + b*16384;
    float acc = 0.0f;
    #pragma unroll
    for (int a = 0; a < 5; a++) {
        int yy = y + a - 2; yy = (yy < 0) ? -yy : ((yy > 127) ? 254 - yy : yy);
        #pragma unroll
        for (int bb = 0; bb < 5; bb++) {
            int xx = x + bb - 2; xx = (xx < 0) ? -xx : ((xx > 127) ? 254 - xx : xx);
            float am = av[cb[yy*128 + xx]];
            float fin = (am < 0.8f) ? 0.0f : am;
            acc += k1[a]*k1[bb]*fin;
        }
    }
    out[OUT_BLUR + p] = acc;
    float amc = av[cb[y*128 + x]];
    float d = each[p] - amc;
    red[tid] = d*d; __syncthreads();
    for (int s = 128; s; s >>= 1) { if (tid < s) red[tid] += red[tid+s]; __syncthreads(); }
    if (tid == 0) tvp[blockIdx.x] = red[0];
}

__global__ __launch_bounds__(128) void k_tvred(const float* __restrict__ tvp, float* __restrict__ out)
{
    __shared__ float red[128];
    int tid = threadIdx.x;
    red[tid] = tvp[tid]; __syncthreads();
    for (int s = 64; s; s >>= 1) { if (tid < s) red[tid] += red[tid+s]; __syncthreads(); }
    if (tid == 0) out[OUT_TV] = red[0] * (1.0f/32768.0f);
}

// ---------------- host ----------------
extern "C" void kernel_launch(void* const* d_in, const int* in_sizes, int n_in,
                              void* d_out, int out_size, void* d_ws, size_t ws_size,
                              hipStream_t stream)
{
    const float* x      = (const float*)d_in[0];
    const float* blend  = (const float*)d_in[11];   // fmap_10
    const float* mw     = (const float*)d_in[27];
    const float* mb     = (const float*)d_in[28];
    const float* afw    = (const float*)d_in[29];
    const float* afb    = (const float*)d_in[30];
    const float* aw     = (const float*)d_in[31];
    const float* ab     = (const float*)d_in[32];
    const float* alw    = (const float*)d_in[33];
    const float* alb    = (const float*)d_in[34];
    const float* istate = (const float*)d_in[35];
    float* out = (float*)d_out;
    float* ws  = (float*)d_ws;

    static const int LN[17] = {0,2,3,5,6,8,9,11,12,14,15,17,18,20,21,23,24};
    FPtrs fp;
    fp.f[0] = (const float*)d_in[26];               // fmap_25
    for (int c = 0; c < 17; c++) fp.f[1+c] = (const float*)d_in[1 + LN[c]];

    float* hA     = ws + WS_HA;
    float* hB     = ws + WS_HB;
    float* st     = ws + WS_ST;
    float* cn     = ws + WS_CN;
    float* biasp  = ws + WS_BIASP;
    float* v      = ws + WS_V;
    int*   choice = (int*)(ws + WS_CHOICE);
    float* part   = ws + WS_PART;
    float* each   = ws + WS_EACH;
    float* bsums  = ws + WS_SUMS;
    int*   bcnts  = (int*)(ws + WS_CNTS);
    float* attv   = ws + WS_ATTV;
    float* tvp    = ws + WS_TVP;

    k_vfold<<<dim3(19), 512, 0, stream>>>(afw, afb, aw, ab, alw, istate, v, biasp, st, cn);
    k_norm<<<14, 256, 0, stream>>>(x, hA);
    k_mlp<<<896, 256, 0, stream>>>(mw, mb, hA, hB, 0, nullptr);
    k_mlp<<<896, 256, 0, stream>>>(mw, mb, hB, hA, 1, nullptr);
    k_mlp<<<896, 256, 0, stream>>>(mw, mb, hA, hB, 2, out + OUT_DZ);
    k_lossdelta<<<1, 256, 0, stream>>>(hB, out + OUT_LD);
    k_zero<<<44, 256, 0, stream>>>(out);
    k_assign<<<512, 256, 0, stream>>>(blend, st, cn, choice);
    k_each<<<NSLAB*64, 256, 0, stream>>>(fp, v, part);
    k_logits<<<128, 256, 0, stream>>>(part, biasp, alb, choice, each, bsums, bcnts);
    k_stats<<<1, 64, 0, stream>>>(bsums, bcnts, attv, out);
    k_final<<<128, 256, 0, stream>>>(each, choice, attv, tvp, out);
    k_tvred<<<1, 128, 0, stream>>>(tvp, out);
}

// Round 4
// 159.652 us; speedup vs baseline: 1.1407x; 1.1407x over previous
//
#include <hip/hip_runtime.h>
#include <math.h>

// ---------------- constants ----------------
#define NPIX 32768            // 2 * 128 * 128
#define OUT_DZ 0
#define OUT_BLUR 18432
#define OUT_LD 51200
#define OUT_REG 51201
#define OUT_TV 51202
#define NSLAB 30

__constant__ int d_cin[18] = {512,512,512,512,512,512,512,512,256,256,128,128,64,64,32,32,16,16};
__constant__ int d_H[18]   = {4,  4,  8,  16, 32, 32, 64, 128,256,256,256,256,256,256,256,256,256,256};

// slab = (layer t, channel chunk c0, chunk size nc)
__constant__ int d_slab_t[NSLAB]  = {0,1,2,3,4,5, 6,6, 7,7,7,7, 8,8,8,8, 9,9,9,9, 10,10, 11,11, 12,13,14,15,16,17};
__constant__ int d_slab_c0[NSLAB] = {0,0,0,0,0,0, 0,256, 0,128,256,384, 0,64,128,192, 0,64,128,192, 0,64, 0,64, 0,0,0,0,0,0};
__constant__ int d_slab_nc[NSLAB] = {512,512,512,512,512,512, 256,256, 128,128,128,128, 64,64,64,64, 64,64,64,64, 64,64, 64,64, 64,64,32,32,16,16};

struct FPtrs { const float* f[18]; };

// ws layout (float offsets)
#define WS_HA     0        // 7168
#define WS_HB     7168     // 7168
#define WS_ST     14336    // 512*16 = 8192  (-2*state transposed, [c][16])
#define WS_CN     22528    // 48
#define WS_BIASP  22576    // 18 (pad to 22656)
#define WS_V      22656    // 18*512 = 9216
#define WS_CHOICE 31872    // 32768 ints
#define WS_PART   64640    // NSLAB*32768 = 983040
#define WS_EACH   1047680  // 32768
#define WS_SUMS   1080448  // 128*20
#define WS_CNTS   1083008  // 128*20 ints
#define WS_ATTV   1085568  // 20
#define WS_TVP    1085600  // 128

// ---------------- small precompute: folded attention vectors + state transpose ----------------
__global__ __launch_bounds__(512) void k_vfold(
    const float* __restrict__ afw, const float* __restrict__ afb,
    const float* __restrict__ aw,  const float* __restrict__ ab,
    const float* __restrict__ alw, const float* __restrict__ istate,
    float* __restrict__ v, float* __restrict__ biasp,
    float* __restrict__ st, float* __restrict__ cn)
{
    int t = blockIdx.x;
    if (t < 18) {
        int cin = d_cin[t];
        const float* w  = (t==0) ? afw : aw + (size_t)(t-1)*32*512;
        const float* bb = (t==0) ? afb : ab + (t-1)*32;
        float scale = (1.0f/sqrtf((float)cin)) * (1.0f/24.0f);   // 1/sqrt(cin) * 1/sqrt(576)
        int c = threadIdx.x;
        if (c < cin) {
            float s = 0.0f;
            #pragma unroll 8
            for (int o = 0; o < 32; o++) s += alw[t*32+o] * w[o*512 + c];
            v[t*512 + c] = s * scale;
        }
        if (threadIdx.x == 0) {
            float s = 0.0f;
            for (int o = 0; o < 32; o++) s += alw[t*32+o] * bb[o];
            biasp[t] = s * (1.0f/24.0f);
        }
    } else {
        int c = threadIdx.x;
        if (c < 512) {
            #pragma unroll
            for (int j = 0; j < 10; j++) st[c*16 + j] = -2.0f * istate[j*576 + c];
        }
        if (c < 10) {
            int j = c;
            float n = 0.0f, s1 = 0.0f, s2 = 0.0f;
            for (int k = 0; k < 576; k++) { float sv = istate[j*576+k]; n += sv*sv; }
            for (int k = 512; k < 544; k++) s1 += istate[j*576+k];
            for (int k = 544; k < 576; k++) s2 += istate[j*576+k];
            cn[j] = n; cn[16+j] = -2.0f*s1; cn[32+j] = -2.0f*s2;
        }
    }
}

// ---------------- cluster assignment (split-K in-block, 8-deep load pipeline) ----------------
__global__ __launch_bounds__(256) void k_assign(
    const float* __restrict__ blend, const float* __restrict__ st,
    const float* __restrict__ cn, int* __restrict__ choice)
{
    __shared__ float gsh[256*10];
    int tid = threadIdx.x;
    int csub = __builtin_amdgcn_readfirstlane(tid >> 6);
    int pl = tid & 63;
    int p = blockIdx.x*64 + pl;
    int b = p >> 14, rem = p & 16383;
    float g[10] = {0,0,0,0,0,0,0,0,0,0};
    const float* src = blend + ((size_t)b*512 + csub*128)*16384 + rem;
    const float* stc = st + csub*128*16;
    for (int c0 = 0; c0 < 128; c0 += 8) {
        float q[8];
        #pragma unroll
        for (int u = 0; u < 8; u++) q[u] = src[(size_t)(c0+u) << 14];
        #pragma unroll
        for (int u = 0; u < 8; u++) {
            #pragma unroll
            for (int j = 0; j < 10; j++) g[j] = fmaf(q[u], stc[(c0+u)*16 + j], g[j]);
        }
    }
    #pragma unroll
    for (int j = 0; j < 10; j++) gsh[tid*10 + j] = g[j];
    __syncthreads();
    if (tid < 64) {
        int pp = blockIdx.x*64 + tid;
        int bb = pp >> 14, rr = pp & 16383, y = rr >> 7, x = rr & 127;
        float cx = (float)x * (float)(2.0/127.0) - 1.0f;
        float cy = (float)y * (float)(2.0/127.0) - 1.0f;
        float gt[10];
        #pragma unroll
        for (int j = 0; j < 10; j++) {
            gt[j] = cn[j] + cn[16+j]*cx + cn[32+j]*cy
                  + gsh[tid*10 + j] + gsh[(64+tid)*10 + j]
                  + gsh[(128+tid)*10 + j] + gsh[(192+tid)*10 + j];
        }
        int best = 0; float bg = gt[0];
        #pragma unroll
        for (int j = 1; j < 10; j++) if (gt[j] < bg) { bg = gt[j]; best = j; }
        choice[pp] = bb*10 + best;
    }
}

// ---------------- mapper: RMS norm ----------------
__global__ __launch_bounds__(256) void k_norm(const float* __restrict__ x, float* __restrict__ h)
{
    int r = blockIdx.x;           // 0..13  (b*7+c)
    int b = r / 7, c = r % 7;
    const float* xr = x + ((size_t)b*18 + c)*512;
    int tid = threadIdx.x;
    float v0 = xr[tid], v1 = xr[tid+256];
    __shared__ float red[256];
    __shared__ float scale;
    red[tid] = v0*v0 + v1*v1; __syncthreads();
    for (int s = 128; s; s >>= 1) { if (tid < s) red[tid] += red[tid+s]; __syncthreads(); }
    if (tid == 0) scale = 1.0f / sqrtf(red[0]*(1.0f/512.0f) + 1e-8f);
    __syncthreads();
    h[r*512 + tid] = v0*scale; h[r*512 + 256 + tid] = v1*scale;
}

// ---------------- mapper: one MLP layer (wave per (c,o), both batches) ----------------
__global__ __launch_bounds__(256) void k_mlp(
    const float* __restrict__ mw, const float* __restrict__ mb,
    const float* __restrict__ hin, float* __restrict__ hout,
    int layer, float* __restrict__ dz)
{
    int wave = blockIdx.x*4 + (threadIdx.x >> 6);
    int lane = threadIdx.x & 63;
    int c = wave >> 9, o = wave & 511;
    const float* wrow = mw + (((size_t)(c*3 + layer)*512 + o) << 9) + lane*8;
    float4 w0 = *(const float4*)wrow;
    float4 w1 = *(const float4*)(wrow + 4);
    const float* h0 = hin + (size_t)c*512 + lane*8;
    const float* h1 = hin + (size_t)(7 + c)*512 + lane*8;
    float4 a0 = *(const float4*)h0, a1 = *(const float4*)(h0+4);
    float4 b0 = *(const float4*)h1, b1 = *(const float4*)(h1+4);
    float d0 = a0.x*w0.x + a0.y*w0.y + a0.z*w0.z + a0.w*w0.w
             + a1.x*w1.x + a1.y*w1.y + a1.z*w1.z + a1.w*w1.w;
    float d1 = b0.x*w0.x + b0.y*w0.y + b0.z*w0.z + b0.w*w0.w
             + b1.x*w1.x + b1.y*w1.y + b1.z*w1.z + b1.w*w1.w;
    #pragma unroll
    for (int m = 32; m; m >>= 1) { d0 += __shfl_xor(d0, m); d1 += __shfl_xor(d1, m); }
    if (lane == 0) {
        const float wsc = (float)(0.1/22.62741699796952);   // 0.1/sqrt(512)
        const float rt2 = 1.41421356237309515f;
        float bias = mb[(c*3 + layer)*512 + o] * 0.1f;
        float z0 = d0*wsc + bias; z0 = (z0 > 0.0f ? z0 : 0.2f*z0) * rt2;
        float z1 = d1*wsc + bias; z1 = (z1 > 0.0f ? z1 : 0.2f*z1) * rt2;
        hout[(size_t)c*512 + o] = z0;
        hout[(size_t)(7 + c)*512 + o] = z1;
        if (dz) {
            dz[((size_t)0*18 + c)*512 + o] = z0;
            dz[((size_t)1*18 + c)*512 + o] = z1;
        }
    }
}

// ---------------- loss_delta ----------------
__global__ __launch_bounds__(256) void k_lossdelta(const float* __restrict__ h, float* __restrict__ outp)
{
    __shared__ float red[256];
    int tid = threadIdx.x;
    float total = 0.0f;
    for (int r = 0; r < 14; r++) {
        float v0 = h[r*512 + tid], v1 = h[r*512 + 256 + tid];
        red[tid] = v0*v0 + v1*v1; __syncthreads();
        for (int s = 128; s; s >>= 1) { if (tid < s) red[tid] += red[tid+s]; __syncthreads(); }
        if (tid == 0) total += sqrtf(red[0]);
        __syncthreads();
    }
    if (tid == 0) outp[0] = total * (1.0f/14.0f);
}

// ---------------- zero tail of delta_zs (layers 7..17) ----------------
__global__ __launch_bounds__(256) void k_zero(float* __restrict__ out)
{
    int z = blockIdx.x*256 + threadIdx.x;   // 0..11263
    if (z < 11264) {
        int b = z / (11*512), rem = z % (11*512);
        out[(size_t)b*18*512 + 7*512 + rem] = 0.0f;
    }
}

// ---------------- balanced folded attention dots (8-deep load pipeline) ----------------
// grid = NSLAB*64 blocks; block: 512 pixels (4 output rows) x one channel chunk.
// thread: 2 adjacent output pixels. Wave = one output row.
__global__ __launch_bounds__(256) void k_each(FPtrs fp, const float* __restrict__ v, float* __restrict__ partial)
{
    __shared__ float vsh[512];
    int s  = blockIdx.x >> 6;
    int px = blockIdx.x & 63;
    int t  = d_slab_t[s];
    int c0 = d_slab_c0[s];
    int nc = d_slab_nc[s];
    int H  = d_H[t];
    int cin = d_cin[t];
    int tid  = threadIdx.x;
    // stage folded vector chunk in LDS (removes per-iter uniform global load)
    for (int i = tid; i < nc; i += 256) vsh[i] = v[t*512 + c0 + i];
    __syncthreads();
    int row  = tid >> 6;          // 0..3
    int lane = tid & 63;
    int pbase = px*512;
    int b = pbase >> 14;
    int y = ((pbase & 16383) >> 7) + row;
    const float* base = fp.f[t] + (size_t)(b*cin + c0) * (size_t)(H*H);
    float a0 = 0.0f, a1 = 0.0f;

    if (H == 256) {
        const float* src = base + (size_t)(2*y)*256 + 4*lane;
        for (int cc = 0; cc < nc; cc += 8) {
            float4 q[8];
            #pragma unroll
            for (int u = 0; u < 8; u++) q[u] = *(const float4*)(src + (size_t)(cc+u)*65536);
            #pragma unroll
            for (int u = 0; u < 8; u++) {
                float vv = vsh[cc+u];
                a0 = fmaf(q[u].x, vv, a0); a1 = fmaf(q[u].z, vv, a1);
            }
        }
    } else if (H == 128) {
        const float* src = base + (size_t)y*128 + 2*lane;
        for (int cc = 0; cc < nc; cc += 8) {
            float2 q[8];
            #pragma unroll
            for (int u = 0; u < 8; u++) q[u] = *(const float2*)(src + (size_t)(cc+u)*16384);
            #pragma unroll
            for (int u = 0; u < 8; u++) {
                float vv = vsh[cc+u];
                a0 = fmaf(q[u].x, vv, a0); a1 = fmaf(q[u].y, vv, a1);
            }
        }
    } else if (H == 64) {
        const float* src = base + (size_t)(y >> 1)*64 + lane;
        for (int cc = 0; cc < nc; cc += 8) {
            float q[8];
            #pragma unroll
            for (int u = 0; u < 8; u++) q[u] = src[(size_t)(cc+u)*4096];
            #pragma unroll
            for (int u = 0; u < 8; u++) {
                float vv = vsh[cc+u];
                a0 = fmaf(q[u], vv, a0); a1 = fmaf(q[u], vv, a1);
            }
        }
    } else {
        int x0 = 2*lane, x1 = 2*lane + 1;
        int sy = (y*H) >> 7, sx0 = (x0*H) >> 7, sx1 = (x1*H) >> 7;
        const float* src = base + (size_t)sy*H;
        size_t HH = (size_t)H*H;
        for (int cc = 0; cc < nc; cc += 8) {
            float q0[8], q1[8];
            #pragma unroll
            for (int u = 0; u < 8; u++) {
                q0[u] = src[(size_t)(cc+u)*HH + sx0];
                q1[u] = src[(size_t)(cc+u)*HH + sx1];
            }
            #pragma unroll
            for (int u = 0; u < 8; u++) {
                float vv = vsh[cc+u];
                a0 = fmaf(q0[u], vv, a0); a1 = fmaf(q1[u], vv, a1);
            }
        }
    }
    int p = pbase + row*128 + 2*lane;
    float2 o; o.x = a0; o.y = a1;
    *(float2*)(partial + (size_t)s*NPIX + p) = o;
}

// ---------------- logits -> sigmoid -> segment partials ----------------
__global__ __launch_bounds__(256) void k_logits(
    const float* __restrict__ partial, const float* __restrict__ biasp,
    const float* __restrict__ alb, const int* __restrict__ choice,
    float* __restrict__ each, float* __restrict__ bsums, int* __restrict__ bcnts)
{
    __shared__ float ssum[20]; __shared__ int scnt[20]; __shared__ float sbias;
    int tid = threadIdx.x;
    if (tid < 20) { ssum[tid] = 0.0f; scnt[tid] = 0; }
    if (tid == 0) {
        float s = alb[0];
        for (int t = 0; t < 18; t++) s += biasp[t];
        sbias = s;
    }
    __syncthreads();
    int p = blockIdx.x*256 + tid;
    float lg = sbias;
    #pragma unroll
    for (int s = 0; s < NSLAB; s++) lg += partial[(size_t)s*NPIX + p];
    float e = 1.0f / (1.0f + expf(-lg));
    each[p] = e;
    int ch = choice[p];
    atomicAdd(&ssum[ch], e);
    atomicAdd(&scnt[ch], 1);
    __syncthreads();
    if (tid < 20) { bsums[blockIdx.x*20 + tid] = ssum[tid]; bcnts[blockIdx.x*20 + tid] = scnt[tid]; }
}

// ---------------- segment stats -> attval, loss_reg ----------------
__global__ __launch_bounds__(64) void k_stats(
    const float* __restrict__ bsums, const int* __restrict__ bcnts,
    float* __restrict__ attv, float* __restrict__ out)
{
    __shared__ float red[32];
    int j = threadIdx.x;
    float regj = 0.0f;
    if (j < 20) {
        float s = 0.0f; int c = 0;
        for (int blk = 0; blk < 128; blk++) { s += bsums[blk*20 + j]; c += bcnts[blk*20 + j]; }
        float mean = s / fmaxf((float)c, 1.0f);
        attv[j] = (c > 0) ? mean : 1.0f;
        regj = (c > 0) ? fmaxf(mean - 0.8f, 0.0f) : 0.0f;
    }
    if (j < 32) red[j] = (j < 20) ? regj : 0.0f;
    __syncthreads();
    for (int s = 16; s; s >>= 1) { if (j < s) red[j] += red[j+s]; __syncthreads(); }
    if (j == 0) out[OUT_REG] = red[0] * 0.5f;   // / batch
}

// ---------------- final map, blur, loss_tv partials ----------------
__global__ __launch_bounds__(256) void k_final(
    const float* __restrict__ each, const int* __restrict__ choice,
    const float* __restrict__ attv, float* __restrict__ tvp, float* __restrict__ out)
{
    __shared__ float av[20];
    __shared__ float red[256];
    int tid = threadIdx.x;
    if (tid < 20) av[tid] = attv[tid];
    __syncthreads();
    int p = blockIdx.x*256 + tid;
    int b = p >> 14, rem = p & 16383, y = rem >> 7, x = rem & 127;
    float k1[5]; float ks = 0.0f;
    #pragma unroll
    for (int i = 0; i < 5; i++) { float d = (float)(i-2) / 1.1f; k1[i] = expf(-0.5f*d*d); ks += k1[i]; }
    #pragma unroll
    for (int i = 0; i < 5; i++) k1[i] /= ks;
    const int* cb = choice + b*16384;
    float acc = 0.0f;
    #pragma unroll
    for (int a = 0; a < 5; a++) {
        int yy = y + a - 2; yy = (yy < 0) ? -yy : ((yy > 127) ? 254 - yy : yy);
        #pragma unroll
        for (int bb = 0; bb < 5; bb++) {
            int xx = x + bb - 2; xx = (xx < 0) ? -xx : ((xx > 127) ? 254 - xx : xx);
            float am = av[cb[yy*128 + xx]];
            float fin = (am < 0.8f) ? 0.0f : am;
            acc += k1[a]*k1[bb]*fin;
        }
    }
    out[OUT_BLUR + p] = acc;
    float amc = av[cb[y*128 + x]];
    float d = each[p] - amc;
    red[tid] = d*d; __syncthreads();
    for (int s = 128; s; s >>= 1) { if (tid < s) red[tid] += red[tid+s]; __syncthreads(); }
    if (tid == 0) tvp[blockIdx.x] = red[0];
}

__global__ __launch_bounds__(128) void k_tvred(const float* __restrict__ tvp, float* __restrict__ out)
{
    __shared__ float red[128];
    int tid = threadIdx.x;
    red[tid] = tvp[tid]; __syncthreads();
    for (int s = 64; s; s >>= 1) { if (tid < s) red[tid] += red[tid+s]; __syncthreads(); }
    if (tid == 0) out[OUT_TV] = red[0] * (1.0f/32768.0f);
}

// ---------------- host ----------------
extern "C" void kernel_launch(void* const* d_in, const int* in_sizes, int n_in,
                              void* d_out, int out_size, void* d_ws, size_t ws_size,
                              hipStream_t stream)
{
    const float* x      = (const float*)d_in[0];
    const float* blend  = (const float*)d_in[11];   // fmap_10
    const float* mw     = (const float*)d_in[27];
    const float* mb     = (const float*)d_in[28];
    const float* afw    = (const float*)d_in[29];
    const float* afb    = (const float*)d_in[30];
    const float* aw     = (const float*)d_in[31];
    const float* ab     = (const float*)d_in[32];
    const float* alw    = (const float*)d_in[33];
    const float* alb    = (const float*)d_in[34];
    const float* istate = (const float*)d_in[35];
    float* out = (float*)d_out;
    float* ws  = (float*)d_ws;

    static const int LN[17] = {0,2,3,5,6,8,9,11,12,14,15,17,18,20,21,23,24};
    FPtrs fp;
    fp.f[0] = (const float*)d_in[26];               // fmap_25
    for (int c = 0; c < 17; c++) fp.f[1+c] = (const float*)d_in[1 + LN[c]];

    float* hA     = ws + WS_HA;
    float* hB     = ws + WS_HB;
    float* st     = ws + WS_ST;
    float* cn     = ws + WS_CN;
    float* biasp  = ws + WS_BIASP;
    float* v      = ws + WS_V;
    int*   choice = (int*)(ws + WS_CHOICE);
    float* part   = ws + WS_PART;
    float* each   = ws + WS_EACH;
    float* bsums  = ws + WS_SUMS;
    int*   bcnts  = (int*)(ws + WS_CNTS);
    float* attv   = ws + WS_ATTV;
    float* tvp    = ws + WS_TVP;

    k_vfold<<<dim3(19), 512, 0, stream>>>(afw, afb, aw, ab, alw, istate, v, biasp, st, cn);
    k_norm<<<14, 256, 0, stream>>>(x, hA);
    k_mlp<<<896, 256, 0, stream>>>(mw, mb, hA, hB, 0, nullptr);
    k_mlp<<<896, 256, 0, stream>>>(mw, mb, hB, hA, 1, nullptr);
    k_mlp<<<896, 256, 0, stream>>>(mw, mb, hA, hB, 2, out + OUT_DZ);
    k_lossdelta<<<1, 256, 0, stream>>>(hB, out + OUT_LD);
    k_zero<<<44, 256, 0, stream>>>(out);
    k_assign<<<512, 256, 0, stream>>>(blend, st, cn, choice);
    k_each<<<NSLAB*64, 256, 0, stream>>>(fp, v, part);
    k_logits<<<128, 256, 0, stream>>>(part, biasp, alb, choice, each, bsums, bcnts);
    k_stats<<<1, 64, 0, stream>>>(bsums, bcnts, attv, out);
    k_final<<<128, 256, 0, stream>>>(each, choice, attv, tvp, out);
    k_tvred<<<1, 128, 0, stream>>>(tvp, out);
}